// Round 5
// baseline (350.150 us; speedup 1.0000x reference)
//
#include <hip/hip_runtime.h>
#include <stdint.h>

// RobertaSelfAttention: B=4, S=2048, HID=1024, NH=16, HD=64. fp32 in/out.
// R5: attn — KT=128 double-buffered K/V tiles, prefetch issued before the
// compute phase so the barrier's vmcnt(0) drain is a no-op (latency-bound
// fix at 2 blocks/CU). 64 q/wave transposed chain (R4) retained.

typedef float f32x4 __attribute__((ext_vector_type(4)));
typedef float f32x16 __attribute__((ext_vector_type(16)));
typedef __bf16 bf16x8 __attribute__((ext_vector_type(8)));
typedef unsigned short ushort_t;
typedef uint32_t u32;

#define MFMA16(a, b, c) __builtin_amdgcn_mfma_f32_16x16x32_bf16(a, b, c, 0, 0, 0)
#define MFMA32(a, b, c) __builtin_amdgcn_mfma_f32_32x32x16_bf16(a, b, c, 0, 0, 0)

__device__ __forceinline__ ushort_t f2b(float f) {
    union { float f; uint32_t u; } x{f};
    uint32_t r = (x.u + 0x7fffu + ((x.u >> 16) & 1u)) >> 16;  // RNE
    return (ushort_t)r;
}

__device__ __forceinline__ float fexp2(float x) {
#if __has_builtin(__builtin_amdgcn_exp2f)
    return __builtin_amdgcn_exp2f(x);
#else
    return exp2f(x);
#endif
}

// pack {bf16(e) lo16, bf16(o) hi16} by byte-perm truncation (e,o > 0)
__device__ __forceinline__ u32 pkpair(float e, float o) {
    union { float f; u32 u; } xe{e}, xo{o};
    return __builtin_amdgcn_perm(xo.u, xe.u, 0x07060302u);
}

__device__ __forceinline__ bf16x8 mk8(u32 a, u32 b, u32 c, u32 d) {
    union { u32 u[4]; bf16x8 v; } x;
    x.u[0] = a; x.u[1] = b; x.u[2] = c; x.u[3] = d;
    return x.v;
}

__device__ __forceinline__ void gld_lds16(const void* g, void* l) {
    __builtin_amdgcn_global_load_lds(
        (const __attribute__((address_space(1))) unsigned int*)g,
        (__attribute__((address_space(3))) unsigned int*)l, 16, 0, 0);
}

// ---------------- fp32 -> bf16 convert: hidden (8M) + Wq/Wk/Wv (3x1M) -------
__global__ __launch_bounds__(256) void convert_k(
    const float* __restrict__ hs, const float* __restrict__ wq,
    const float* __restrict__ wk, const float* __restrict__ wv,
    ushort_t* __restrict__ hs_b, ushort_t* __restrict__ w_b) {
    size_t c = (size_t)blockIdx.x * 256 + threadIdx.x;
    size_t i = c * 8;
    const size_t NHS = (size_t)8192 * 1024;
    const float* src;
    ushort_t* dst;
    if (i < NHS) { src = hs + i; dst = hs_b + i; }
    else {
        size_t j = i - NHS;
        int w = (int)(j >> 20);
        size_t o = j & ((1u << 20) - 1);
        src = (w == 0 ? wq : (w == 1 ? wk : wv)) + o;
        dst = w_b + ((size_t)w << 20) + o;
    }
    float4 a = *(const float4*)src;
    float4 b = *(const float4*)(src + 4);
    uint32_t p0 = (uint32_t)f2b(a.x) | ((uint32_t)f2b(a.y) << 16);
    uint32_t p1 = (uint32_t)f2b(a.z) | ((uint32_t)f2b(a.w) << 16);
    uint32_t p2 = (uint32_t)f2b(b.x) | ((uint32_t)f2b(b.y) << 16);
    uint32_t p3 = (uint32_t)f2b(b.z) | ((uint32_t)f2b(b.w) << 16);
    uint4 v{p0, p1, p2, p3};
    *(uint4*)dst = v;
}

// ---------------- QKV projection GEMM (unchanged from R4) -------------------
__global__ __launch_bounds__(256, 2) void qkv_gemm(
    const ushort_t* __restrict__ Ab, const ushort_t* __restrict__ Wb,
    const float* __restrict__ bq, const float* __restrict__ bk,
    const float* __restrict__ bv, ushort_t* __restrict__ q_ws,
    ushort_t* __restrict__ k_ws, ushort_t* __restrict__ vt_ws) {
    __shared__ __align__(16) char smem_raw[128 * 136 * 2];  // 34816 B
    ushort_t* At = (ushort_t*)smem_raw;        // [128][64]
    ushort_t* Bt = At + 128 * 64;              // [128][64]
    ushort_t* Ct = (ushort_t*)smem_raw;        // [128][stride 136] overlay
    int which = blockIdx.z;
    const ushort_t* W = Wb + ((size_t)which << 20);
    int m0 = blockIdx.y * 128, n0 = blockIdx.x * 128;
    int t = threadIdx.x, lane = t & 63, wave = t >> 6;
    int quad = lane >> 4, l16 = lane & 15;
    int wr = (wave >> 1) * 64, wc = (wave & 1) * 64;
    f32x4 acc[4][4] = {};
    for (int k0 = 0; k0 < 1024; k0 += 64) {
        for (int r = 0; r < 4; r++) {
            int idx = r * 256 + t;
            int row = idx >> 3, co = (idx & 7) * 8;
            gld_lds16(Ab + (size_t)(m0 + row) * 1024 + k0 + co, At + idx * 8);
            gld_lds16(W + (size_t)(n0 + row) * 1024 + k0 + co, Bt + idx * 8);
        }
        asm volatile("s_waitcnt vmcnt(0)" ::: "memory");
        __syncthreads();
        for (int kk = 0; kk < 2; kk++) {
            bf16x8 af[4], bf[4];
            for (int i = 0; i < 4; i++)
                af[i] = *(const bf16x8*)(At + (wr + i * 16 + l16) * 64 + kk * 32 + quad * 8);
            for (int j = 0; j < 4; j++)
                bf[j] = *(const bf16x8*)(Bt + (wc + j * 16 + l16) * 64 + kk * 32 + quad * 8);
            for (int i = 0; i < 4; i++)
                for (int j = 0; j < 4; j++)
                    acc[i][j] = MFMA16(af[i], bf[j], acc[i][j]);
        }
        __syncthreads();
    }
    const float* bias = which == 0 ? bq : (which == 1 ? bk : bv);
    float sc = which == 0 ? (0.125f * 1.44269504f) : 1.0f;  // 1/sqrt(HD)*log2e
    if (which == 2) {
        for (int j = 0; j < 4; j++) {
            float bias_v = bias[n0 + wc + j * 16 + l16];
            for (int i = 0; i < 4; i++) {
                ushort4 pk;
                pk.x = f2b(acc[i][j].x + bias_v);
                pk.y = f2b(acc[i][j].y + bias_v);
                pk.z = f2b(acc[i][j].z + bias_v);
                pk.w = f2b(acc[i][j].w + bias_v);
                *(ushort4*)(Ct + (wc + j * 16 + l16) * 136 + wr + i * 16 + quad * 4) = pk;
            }
        }
    } else {
        for (int j = 0; j < 4; j++) {
            float bias_v = bias[n0 + wc + j * 16 + l16];
            int col = wc + j * 16 + l16;
            for (int i = 0; i < 4; i++) {
                int rb = wr + i * 16 + quad * 4;
                Ct[(rb + 0) * 136 + col] = f2b((acc[i][j].x + bias_v) * sc);
                Ct[(rb + 1) * 136 + col] = f2b((acc[i][j].y + bias_v) * sc);
                Ct[(rb + 2) * 136 + col] = f2b((acc[i][j].z + bias_v) * sc);
                Ct[(rb + 3) * 136 + col] = f2b((acc[i][j].w + bias_v) * sc);
            }
        }
    }
    __syncthreads();
    for (int r = 0; r < 8; r++) {
        int idx = r * 256 + t;
        int row = idx >> 4, c8 = (idx & 15) * 8;
        uint4 val = *(const uint4*)(Ct + row * 136 + c8);
        if (which == 2) {
            int col = n0 + row, h = col >> 6, d = col & 63;
            int tok = m0 + c8, b = tok >> 11, s = tok & 2047;
            *(uint4*)(vt_ws + ((size_t)(b * 16 + h) * 64 + d) * 2048 + s) = val;
        } else {
            int tok = m0 + row, b = tok >> 11, s = tok & 2047;
            int col = n0 + c8, h = col >> 6, d = col & 63;
            ushort_t* base = which == 0 ? q_ws : k_ws;
            *(uint4*)(base + ((size_t)(b * 16 + h) * 2048 + s) * 64 + d) = val;
        }
    }
}

// ---------------- flash attention: 64 q/wave, KT=128, LDS double-buffer ----
// Per round: barrier -> issue next tile's gld_lds (async) -> compute 2x64-key
// passes on current buffer. Prefetch latency hidden behind ~1500cyc compute.
__global__ __launch_bounds__(256, 2) void attn_k(
    const ushort_t* __restrict__ q_ws, const ushort_t* __restrict__ k_ws,
    const ushort_t* __restrict__ vt_ws, const float* __restrict__ mask,
    float* __restrict__ out) {
    __shared__ __align__(16) char smraw[65536];  // 2 x (K 16KB + Vt 16KB)
    float* Ow = (float*)smraw;                   // epilogue overlay [128][65]

    int bh = blockIdx.y, b = bh >> 4, h = bh & 15;
    int q0 = blockIdx.x * 256;
    int t = threadIdx.x, lane = t & 63, w = t >> 6;
    int l31 = lane & 31, hi = lane >> 5;
    bool h0 = (hi == 0);
    const ushort_t* Q = q_ws + (size_t)bh * 2048 * 64;
    const ushort_t* K = k_ws + (size_t)bh * 2048 * 64;
    const ushort_t* Vt = vt_ws + (size_t)bh * 64 * 2048;
    const float* mrow = mask + b * 2048;

    bf16x8 qf[2][4];
#pragma unroll
    for (int qg = 0; qg < 2; qg++)
#pragma unroll
        for (int cs = 0; cs < 4; cs++)
            qf[qg][cs] = *(const bf16x8*)(
                Q + (size_t)(q0 + w * 64 + qg * 32 + l31) * 64 + cs * 16 + hi * 8);
    int co[4];   // K-frag chunk offsets (64-short rows, mod-8 swizzle)
#pragma unroll
    for (int cs = 0; cs < 4; cs++) co[cs] = ((cs * 2 + hi) ^ (l31 & 7)) * 8;

    f32x16 o00 = {}, o01 = {}, o10 = {}, o11 = {};
    float rs0 = 0.f, rs1 = 0.f;

    // stage tile t0 into buffer bufi: K[128][64] mod-8 swizzle,
    // Vt[64][128] mod-16 swizzle (256B rows)
    auto stage = [&](int bufi, int t0) {
        ushort_t* Klb = (ushort_t*)(smraw + bufi * 32768);
        ushort_t* Vtlb = Klb + 8192;
#pragma unroll
        for (int it = 0; it < 4; it++) {
            int idx = it * 256 + t;
            int krow = idx >> 3, kch = idx & 7;
            gld_lds16(K + (size_t)(t0 + krow) * 64 + ((kch ^ (krow & 7)) * 8),
                      Klb + idx * 8);
            int vrow = idx >> 4, vch = idx & 15;
            gld_lds16(Vt + (size_t)vrow * 2048 + t0 + ((vch ^ (vrow & 15)) * 8),
                      Vtlb + idx * 8);
        }
    };

    stage(0, 0);
    int buf = 0;
    for (int t0 = 0; t0 < 2048; t0 += 128) {
        asm volatile("s_waitcnt vmcnt(0)" ::: "memory");
        __syncthreads();
        if (t0 + 128 < 2048) stage(buf ^ 1, t0 + 128);
        ushort_t* Klb = (ushort_t*)(smraw + buf * 32768);
        ushort_t* Vtlb = Klb + 8192;
#pragma unroll
        for (int kh = 0; kh < 2; kh++) {
            int kb = kh * 64;
            // S^T = K · Q^T for both q-groups (K frags shared)
            f32x16 s00 = {}, s01 = {}, s10 = {}, s11 = {};
#pragma unroll
            for (int cs = 0; cs < 4; cs++) {
                bf16x8 k0 = *(const bf16x8*)(Klb + (kb + l31) * 64 + co[cs]);
                bf16x8 k1 = *(const bf16x8*)(Klb + (kb + 32 + l31) * 64 + co[cs]);
                s00 = MFMA32(k0, qf[0][cs], s00);
                s01 = MFMA32(k1, qf[0][cs], s01);
                s10 = MFMA32(k0, qf[1][cs], s10);
                s11 = MFMA32(k1, qf[1][cs], s11);
            }
            // exp2 + pack + P^T B-frags per q-group
            bf16x8 pfr[2][4];
#pragma unroll
            for (int qg = 0; qg < 2; qg++) {
                const f32x16& sa = qg ? s10 : s00;
                const f32x16& sb = qg ? s11 : s01;
                u32 pa[8], pb[8];
                float rst = 0.f;
#pragma unroll
                for (int i = 0; i < 4; i++) {
                    float4 bm = *(const float4*)(mrow + t0 + kb + 8 * i + 4 * hi);
                    float e0 = fexp2(fmaf(bm.x, 1.44269504f, sa[4 * i + 0]));
                    float e1 = fexp2(fmaf(bm.y, 1.44269504f, sa[4 * i + 1]));
                    float e2 = fexp2(fmaf(bm.z, 1.44269504f, sa[4 * i + 2]));
                    float e3 = fexp2(fmaf(bm.w, 1.44269504f, sa[4 * i + 3]));
                    rst += (e0 + e1) + (e2 + e3);
                    pa[2 * i] = pkpair(e0, e1);
                    pa[2 * i + 1] = pkpair(e2, e3);
                }
#pragma unroll
                for (int i = 0; i < 4; i++) {
                    float4 bm = *(const float4*)(mrow + t0 + kb + 32 + 8 * i + 4 * hi);
                    float e0 = fexp2(fmaf(bm.x, 1.44269504f, sb[4 * i + 0]));
                    float e1 = fexp2(fmaf(bm.y, 1.44269504f, sb[4 * i + 1]));
                    float e2 = fexp2(fmaf(bm.z, 1.44269504f, sb[4 * i + 2]));
                    float e3 = fexp2(fmaf(bm.w, 1.44269504f, sb[4 * i + 3]));
                    rst += (e0 + e1) + (e2 + e3);
                    pb[2 * i] = pkpair(e0, e1);
                    pb[2 * i + 1] = pkpair(e2, e3);
                }
                if (qg == 0) rs0 += rst; else rs1 += rst;
#pragma unroll
                for (int g = 0; g < 4; g++) {
                    const u32* aa = (g < 2) ? pa : pb;
                    int base = (g & 1) * 4;
                    u32 y0 = h0 ? aa[base + 2] : aa[base + 0];
                    u32 y1 = h0 ? aa[base + 3] : aa[base + 1];
                    u32 sy0 = (u32)__shfl_xor((int)y0, 32, 64);
                    u32 sy1 = (u32)__shfl_xor((int)y1, 32, 64);
                    pfr[qg][g] = mk8(h0 ? aa[base + 0] : sy0, h0 ? aa[base + 1] : sy1,
                                     h0 ? sy0 : aa[base + 2], h0 ? sy1 : aa[base + 3]);
                }
            }
            // O^T += V^T · P^T (V frags shared; mod-16 swizzle in 128-short rows)
#pragma unroll
            for (int cs = 0; cs < 4; cs++) {
                int vc0 = ((kh * 8 + cs * 2 + hi) ^ (l31 & 15)) * 8;
                bf16x8 v0 = *(const bf16x8*)(Vtlb + l31 * 128 + vc0);
                bf16x8 v1 = *(const bf16x8*)(Vtlb + (32 + l31) * 128 + vc0);
                o00 = MFMA32(v0, pfr[0][cs], o00);
                o01 = MFMA32(v1, pfr[0][cs], o01);
                o10 = MFMA32(v0, pfr[1][cs], o10);
                o11 = MFMA32(v1, pfr[1][cs], o11);
            }
        }
        buf ^= 1;
    }
    rs0 += __shfl_xor(rs0, 32, 64);
    rs1 += __shfl_xor(rs1, 32, 64);
    float inv0 = 1.f / rs0, inv1 = 1.f / rs1;
    __syncthreads();  // all waves done reading K/V buffers before Ow overlay
    // epilogue: per q-group, O^T -> LDS transpose -> coalesced f32x4 stores
#pragma unroll
    for (int qg = 0; qg < 2; qg++) {
        float inv = qg ? inv1 : inv0;
        const f32x16& a0 = qg ? o10 : o00;
        const f32x16& a1 = qg ? o11 : o01;
#pragma unroll
        for (int g = 0; g < 4; g++) {
            f32x4 c0, c1;
#pragma unroll
            for (int r = 0; r < 4; r++) {
                c0[r] = a0[4 * g + r] * inv;
                c1[r] = a1[4 * g + r] * inv;
            }
            *(f32x4*)(Ow + (w * 32 + l31) * 65 + 8 * g + 4 * hi) = c0;
            *(f32x4*)(Ow + (w * 32 + l31) * 65 + 32 + 8 * g + 4 * hi) = c1;
        }
        __syncthreads();
#pragma unroll
        for (int cc = 0; cc < 8; cc++) {
            int c = cc * 256 + t;
            int row = c >> 4, seg = (c & 15) * 4;
            f32x4 vv = *(const f32x4*)(Ow + row * 65 + seg);
            int ql = (row >> 5) * 64 + qg * 32 + (row & 31);
            *(f32x4*)(out + ((size_t)(b * 2048 + q0 + ql)) * 1024 + h * 64 + seg) = vv;
        }
        __syncthreads();
    }
}

extern "C" void kernel_launch(void* const* d_in, const int* in_sizes, int n_in,
                              void* d_out, int out_size, void* d_ws, size_t ws_size,
                              hipStream_t stream) {
    const float* hs = (const float*)d_in[0];
    const float* mask = (const float*)d_in[1];
    const float* wq = (const float*)d_in[2];
    const float* bq = (const float*)d_in[3];
    const float* wk = (const float*)d_in[4];
    const float* bk = (const float*)d_in[5];
    const float* wv = (const float*)d_in[6];
    const float* bv = (const float*)d_in[7];
    float* out = (float*)d_out;
    char* ws = (char*)d_ws;
    ushort_t* hs_b = (ushort_t*)ws;
    ushort_t* w_b = (ushort_t*)(ws + 16777216);
    ushort_t* q_ws = (ushort_t*)(ws + 23068672);
    ushort_t* k_ws = (ushort_t*)(ws + 39845888);
    ushort_t* vt_ws = (ushort_t*)(ws + 56623104);

    convert_k<<<5632, 256, 0, stream>>>(hs, wq, wk, wv, hs_b, w_b);
    qkv_gemm<<<dim3(8, 64, 3), 256, 0, stream>>>(hs_b, w_b, bq, bk, bv, q_ws, k_ws, vt_ws);
    attn_k<<<dim3(8, 64), 256, 0, stream>>>(q_ws, k_ws, vt_ws, mask, out);
}

// Round 6
// 258.722 us; speedup vs baseline: 1.3534x; 1.3534x over previous
//
#include <hip/hip_runtime.h>
#include <stdint.h>

// RobertaSelfAttention: B=4, S=2048, HID=1024, NH=16, HD=64. fp32 in/out.
// R6: attn_k reverted to R4 (R5 dbuf caused VGPR spill -> 215MB scratch
// writes). qkv_gemm occupancy 2->4 blocks/CU (launch_bounds(256,4)): the
// 16-iteration K-loop is latency-bound on its per-iter vmcnt(0)+barrier
// drain at 2 blocks/CU.

typedef float f32x4 __attribute__((ext_vector_type(4)));
typedef float f32x16 __attribute__((ext_vector_type(16)));
typedef __bf16 bf16x8 __attribute__((ext_vector_type(8)));
typedef unsigned short ushort_t;
typedef uint32_t u32;

#define MFMA16(a, b, c) __builtin_amdgcn_mfma_f32_16x16x32_bf16(a, b, c, 0, 0, 0)
#define MFMA32(a, b, c) __builtin_amdgcn_mfma_f32_32x32x16_bf16(a, b, c, 0, 0, 0)

__device__ __forceinline__ ushort_t f2b(float f) {
    union { float f; uint32_t u; } x{f};
    uint32_t r = (x.u + 0x7fffu + ((x.u >> 16) & 1u)) >> 16;  // RNE
    return (ushort_t)r;
}

__device__ __forceinline__ float fexp2(float x) {
#if __has_builtin(__builtin_amdgcn_exp2f)
    return __builtin_amdgcn_exp2f(x);
#else
    return exp2f(x);
#endif
}

// pack {bf16(e) lo16, bf16(o) hi16} by byte-perm truncation (e,o > 0)
__device__ __forceinline__ u32 pkpair(float e, float o) {
    union { float f; u32 u; } xe{e}, xo{o};
    return __builtin_amdgcn_perm(xo.u, xe.u, 0x07060302u);
}

__device__ __forceinline__ bf16x8 mk8(u32 a, u32 b, u32 c, u32 d) {
    union { u32 u[4]; bf16x8 v; } x;
    x.u[0] = a; x.u[1] = b; x.u[2] = c; x.u[3] = d;
    return x.v;
}

__device__ __forceinline__ void gld_lds16(const void* g, void* l) {
    __builtin_amdgcn_global_load_lds(
        (const __attribute__((address_space(1))) unsigned int*)g,
        (__attribute__((address_space(3))) unsigned int*)l, 16, 0, 0);
}

// ---------------- fp32 -> bf16 convert: hidden (8M) + Wq/Wk/Wv (3x1M) -------
__global__ __launch_bounds__(256) void convert_k(
    const float* __restrict__ hs, const float* __restrict__ wq,
    const float* __restrict__ wk, const float* __restrict__ wv,
    ushort_t* __restrict__ hs_b, ushort_t* __restrict__ w_b) {
    size_t c = (size_t)blockIdx.x * 256 + threadIdx.x;
    size_t i = c * 8;
    const size_t NHS = (size_t)8192 * 1024;
    const float* src;
    ushort_t* dst;
    if (i < NHS) { src = hs + i; dst = hs_b + i; }
    else {
        size_t j = i - NHS;
        int w = (int)(j >> 20);
        size_t o = j & ((1u << 20) - 1);
        src = (w == 0 ? wq : (w == 1 ? wk : wv)) + o;
        dst = w_b + ((size_t)w << 20) + o;
    }
    float4 a = *(const float4*)src;
    float4 b = *(const float4*)(src + 4);
    uint32_t p0 = (uint32_t)f2b(a.x) | ((uint32_t)f2b(a.y) << 16);
    uint32_t p1 = (uint32_t)f2b(a.z) | ((uint32_t)f2b(a.w) << 16);
    uint32_t p2 = (uint32_t)f2b(b.x) | ((uint32_t)f2b(b.y) << 16);
    uint32_t p3 = (uint32_t)f2b(b.z) | ((uint32_t)f2b(b.w) << 16);
    uint4 v{p0, p1, p2, p3};
    *(uint4*)dst = v;
}

// ---------------- QKV projection GEMM: 4 blocks/CU ----------------
__global__ __launch_bounds__(256, 4) void qkv_gemm(
    const ushort_t* __restrict__ Ab, const ushort_t* __restrict__ Wb,
    const float* __restrict__ bq, const float* __restrict__ bk,
    const float* __restrict__ bv, ushort_t* __restrict__ q_ws,
    ushort_t* __restrict__ k_ws, ushort_t* __restrict__ vt_ws) {
    __shared__ __align__(16) char smem_raw[128 * 136 * 2];  // 34816 B
    ushort_t* At = (ushort_t*)smem_raw;        // [128][64]
    ushort_t* Bt = At + 128 * 64;              // [128][64]
    ushort_t* Ct = (ushort_t*)smem_raw;        // [128][stride 136] overlay
    int which = blockIdx.z;
    const ushort_t* W = Wb + ((size_t)which << 20);
    int m0 = blockIdx.y * 128, n0 = blockIdx.x * 128;
    int t = threadIdx.x, lane = t & 63, wave = t >> 6;
    int quad = lane >> 4, l16 = lane & 15;
    int wr = (wave >> 1) * 64, wc = (wave & 1) * 64;
    f32x4 acc[4][4] = {};
    for (int k0 = 0; k0 < 1024; k0 += 64) {
        for (int r = 0; r < 4; r++) {
            int idx = r * 256 + t;
            int row = idx >> 3, co = (idx & 7) * 8;
            gld_lds16(Ab + (size_t)(m0 + row) * 1024 + k0 + co, At + idx * 8);
            gld_lds16(W + (size_t)(n0 + row) * 1024 + k0 + co, Bt + idx * 8);
        }
        asm volatile("s_waitcnt vmcnt(0)" ::: "memory");
        __syncthreads();
        for (int kk = 0; kk < 2; kk++) {
            bf16x8 af[4], bf[4];
            for (int i = 0; i < 4; i++)
                af[i] = *(const bf16x8*)(At + (wr + i * 16 + l16) * 64 + kk * 32 + quad * 8);
            for (int j = 0; j < 4; j++)
                bf[j] = *(const bf16x8*)(Bt + (wc + j * 16 + l16) * 64 + kk * 32 + quad * 8);
            for (int i = 0; i < 4; i++)
                for (int j = 0; j < 4; j++)
                    acc[i][j] = MFMA16(af[i], bf[j], acc[i][j]);
        }
        __syncthreads();
    }
    const float* bias = which == 0 ? bq : (which == 1 ? bk : bv);
    float sc = which == 0 ? (0.125f * 1.44269504f) : 1.0f;  // 1/sqrt(HD)*log2e
    if (which == 2) {
        for (int j = 0; j < 4; j++) {
            float bias_v = bias[n0 + wc + j * 16 + l16];
            for (int i = 0; i < 4; i++) {
                ushort4 pk;
                pk.x = f2b(acc[i][j].x + bias_v);
                pk.y = f2b(acc[i][j].y + bias_v);
                pk.z = f2b(acc[i][j].z + bias_v);
                pk.w = f2b(acc[i][j].w + bias_v);
                *(ushort4*)(Ct + (wc + j * 16 + l16) * 136 + wr + i * 16 + quad * 4) = pk;
            }
        }
    } else {
        for (int j = 0; j < 4; j++) {
            float bias_v = bias[n0 + wc + j * 16 + l16];
            int col = wc + j * 16 + l16;
            for (int i = 0; i < 4; i++) {
                int rb = wr + i * 16 + quad * 4;
                Ct[(rb + 0) * 136 + col] = f2b((acc[i][j].x + bias_v) * sc);
                Ct[(rb + 1) * 136 + col] = f2b((acc[i][j].y + bias_v) * sc);
                Ct[(rb + 2) * 136 + col] = f2b((acc[i][j].z + bias_v) * sc);
                Ct[(rb + 3) * 136 + col] = f2b((acc[i][j].w + bias_v) * sc);
            }
        }
    }
    __syncthreads();
    for (int r = 0; r < 8; r++) {
        int idx = r * 256 + t;
        int row = idx >> 4, c8 = (idx & 15) * 8;
        uint4 val = *(const uint4*)(Ct + row * 136 + c8);
        if (which == 2) {
            int col = n0 + row, h = col >> 6, d = col & 63;
            int tok = m0 + c8, b = tok >> 11, s = tok & 2047;
            *(uint4*)(vt_ws + ((size_t)(b * 16 + h) * 64 + d) * 2048 + s) = val;
        } else {
            int tok = m0 + row, b = tok >> 11, s = tok & 2047;
            int col = n0 + c8, h = col >> 6, d = col & 63;
            ushort_t* base = which == 0 ? q_ws : k_ws;
            *(uint4*)(base + ((size_t)(b * 16 + h) * 2048 + s) * 64 + d) = val;
        }
    }
}

// ---------------- flash attention (R4 version, verbatim) --------------------
__global__ __launch_bounds__(256, 2) void attn_k(
    const ushort_t* __restrict__ q_ws, const ushort_t* __restrict__ k_ws,
    const ushort_t* __restrict__ vt_ws, const float* __restrict__ mask,
    float* __restrict__ out) {
    __shared__ __align__(16) char smraw[33280];
    ushort_t* Kl = (ushort_t*)smraw;          // [64 key][64 d] xor-swizzled
    ushort_t* Vtl = Kl + 64 * 64;             // [64 d][64 key] xor-swizzled
    float* Ow = (float*)smraw;                // epilogue overlay [128][65]

    int bh = blockIdx.y, b = bh >> 4, h = bh & 15;
    int q0 = blockIdx.x * 256;
    int t = threadIdx.x, lane = t & 63, w = t >> 6;
    int l31 = lane & 31, hi = lane >> 5;
    bool h0 = (hi == 0);
    const ushort_t* Q = q_ws + (size_t)bh * 2048 * 64;
    const ushort_t* K = k_ws + (size_t)bh * 2048 * 64;
    const ushort_t* Vt = vt_ws + (size_t)bh * 64 * 2048;
    const float* mrow = mask + b * 2048;

    bf16x8 qf[2][4];
#pragma unroll
    for (int qg = 0; qg < 2; qg++)
#pragma unroll
        for (int cs = 0; cs < 4; cs++)
            qf[qg][cs] = *(const bf16x8*)(
                Q + (size_t)(q0 + w * 64 + qg * 32 + l31) * 64 + cs * 16 + hi * 8);
    int co[4];
#pragma unroll
    for (int cs = 0; cs < 4; cs++) co[cs] = ((cs * 2 + hi) ^ (l31 & 7)) * 8;

    f32x16 o00 = {}, o01 = {}, o10 = {}, o11 = {};
    float rs0 = 0.f, rs1 = 0.f;

    for (int t0 = 0; t0 < 2048; t0 += 64) {
        // stage K [64 key][64 d] and Vt [64 d][64 key], xor-swizzled source
#pragma unroll
        for (int it = 0; it < 2; it++) {
            int idx = it * 256 + t;
            int row = idx >> 3, ch = idx & 7;
            int sch = (ch ^ (row & 7)) * 8;
            gld_lds16(K + (size_t)(t0 + row) * 64 + sch, Kl + idx * 8);
            gld_lds16(Vt + (size_t)row * 2048 + t0 + sch, Vtl + idx * 8);
        }
        asm volatile("s_waitcnt vmcnt(0)" ::: "memory");
        __syncthreads();
        // S^T = K · Q^T for both q-groups (K frags shared)
        f32x16 s00 = {}, s01 = {}, s10 = {}, s11 = {};
#pragma unroll
        for (int cs = 0; cs < 4; cs++) {
            bf16x8 k0 = *(const bf16x8*)(Kl + l31 * 64 + co[cs]);
            bf16x8 k1 = *(const bf16x8*)(Kl + (32 + l31) * 64 + co[cs]);
            s00 = MFMA32(k0, qf[0][cs], s00);
            s01 = MFMA32(k1, qf[0][cs], s01);
            s10 = MFMA32(k0, qf[1][cs], s10);
            s11 = MFMA32(k1, qf[1][cs], s11);
        }
        // exp2 + pack + P^T B-frags per q-group
        bf16x8 pfr[2][4];
#pragma unroll
        for (int qg = 0; qg < 2; qg++) {
            const f32x16& sa = qg ? s10 : s00;
            const f32x16& sb = qg ? s11 : s01;
            u32 pa[8], pb[8];
            float rst = 0.f;
#pragma unroll
            for (int i = 0; i < 4; i++) {
                float4 bm = *(const float4*)(mrow + t0 + 8 * i + 4 * hi);
                float e0 = fexp2(fmaf(bm.x, 1.44269504f, sa[4 * i + 0]));
                float e1 = fexp2(fmaf(bm.y, 1.44269504f, sa[4 * i + 1]));
                float e2 = fexp2(fmaf(bm.z, 1.44269504f, sa[4 * i + 2]));
                float e3 = fexp2(fmaf(bm.w, 1.44269504f, sa[4 * i + 3]));
                rst += (e0 + e1) + (e2 + e3);
                pa[2 * i] = pkpair(e0, e1);
                pa[2 * i + 1] = pkpair(e2, e3);
            }
#pragma unroll
            for (int i = 0; i < 4; i++) {
                float4 bm = *(const float4*)(mrow + t0 + 32 + 8 * i + 4 * hi);
                float e0 = fexp2(fmaf(bm.x, 1.44269504f, sb[4 * i + 0]));
                float e1 = fexp2(fmaf(bm.y, 1.44269504f, sb[4 * i + 1]));
                float e2 = fexp2(fmaf(bm.z, 1.44269504f, sb[4 * i + 2]));
                float e3 = fexp2(fmaf(bm.w, 1.44269504f, sb[4 * i + 3]));
                rst += (e0 + e1) + (e2 + e3);
                pb[2 * i] = pkpair(e0, e1);
                pb[2 * i + 1] = pkpair(e2, e3);
            }
            if (qg == 0) rs0 += rst; else rs1 += rst;
#pragma unroll
            for (int g = 0; g < 4; g++) {
                const u32* aa = (g < 2) ? pa : pb;
                int base = (g & 1) * 4;
                u32 y0 = h0 ? aa[base + 2] : aa[base + 0];
                u32 y1 = h0 ? aa[base + 3] : aa[base + 1];
                u32 sy0 = (u32)__shfl_xor((int)y0, 32, 64);
                u32 sy1 = (u32)__shfl_xor((int)y1, 32, 64);
                pfr[qg][g] = mk8(h0 ? aa[base + 0] : sy0, h0 ? aa[base + 1] : sy1,
                                 h0 ? sy0 : aa[base + 2], h0 ? sy1 : aa[base + 3]);
            }
        }
        // O^T += V^T · P^T for both q-groups (V frags shared)
#pragma unroll
        for (int cs = 0; cs < 4; cs++) {
            bf16x8 v0 = *(const bf16x8*)(Vtl + l31 * 64 + co[cs]);
            bf16x8 v1 = *(const bf16x8*)(Vtl + (32 + l31) * 64 + co[cs]);
            o00 = MFMA32(v0, pfr[0][cs], o00);
            o01 = MFMA32(v1, pfr[0][cs], o01);
            o10 = MFMA32(v0, pfr[1][cs], o10);
            o11 = MFMA32(v1, pfr[1][cs], o11);
        }
        __syncthreads();
    }
    rs0 += __shfl_xor(rs0, 32, 64);
    rs1 += __shfl_xor(rs1, 32, 64);
    float inv0 = 1.f / rs0, inv1 = 1.f / rs1;
    // epilogue: per q-group, O^T -> LDS transpose -> coalesced f32x4 stores
#pragma unroll
    for (int qg = 0; qg < 2; qg++) {
        float inv = qg ? inv1 : inv0;
        const f32x16& a0 = qg ? o10 : o00;
        const f32x16& a1 = qg ? o11 : o01;
#pragma unroll
        for (int g = 0; g < 4; g++) {
            f32x4 c0, c1;
#pragma unroll
            for (int r = 0; r < 4; r++) {
                c0[r] = a0[4 * g + r] * inv;
                c1[r] = a1[4 * g + r] * inv;
            }
            *(f32x4*)(Ow + (w * 32 + l31) * 65 + 8 * g + 4 * hi) = c0;
            *(f32x4*)(Ow + (w * 32 + l31) * 65 + 32 + 8 * g + 4 * hi) = c1;
        }
        __syncthreads();
#pragma unroll
        for (int cc = 0; cc < 8; cc++) {
            int c = cc * 256 + t;
            int row = c >> 4, seg = (c & 15) * 4;
            f32x4 vv = *(const f32x4*)(Ow + row * 65 + seg);
            int ql = (row >> 5) * 64 + qg * 32 + (row & 31);
            *(f32x4*)(out + ((size_t)(b * 2048 + q0 + ql)) * 1024 + h * 64 + seg) = vv;
        }
        __syncthreads();
    }
}

extern "C" void kernel_launch(void* const* d_in, const int* in_sizes, int n_in,
                              void* d_out, int out_size, void* d_ws, size_t ws_size,
                              hipStream_t stream) {
    const float* hs = (const float*)d_in[0];
    const float* mask = (const float*)d_in[1];
    const float* wq = (const float*)d_in[2];
    const float* bq = (const float*)d_in[3];
    const float* wk = (const float*)d_in[4];
    const float* bk = (const float*)d_in[5];
    const float* wv = (const float*)d_in[6];
    const float* bv = (const float*)d_in[7];
    float* out = (float*)d_out;
    char* ws = (char*)d_ws;
    ushort_t* hs_b = (ushort_t*)ws;
    ushort_t* w_b = (ushort_t*)(ws + 16777216);
    ushort_t* q_ws = (ushort_t*)(ws + 23068672);
    ushort_t* k_ws = (ushort_t*)(ws + 39845888);
    ushort_t* vt_ws = (ushort_t*)(ws + 56623104);

    convert_k<<<5632, 256, 0, stream>>>(hs, wq, wk, wv, hs_b, w_b);
    qkv_gemm<<<dim3(8, 64, 3), 256, 0, stream>>>(hs_b, w_b, bq, bk, bv, q_ws, k_ws, vt_ws);
    attn_k<<<dim3(8, 64), 256, 0, stream>>>(q_ws, k_ws, vt_ws, mask, out);
}

// Round 7
// 257.796 us; speedup vs baseline: 1.3582x; 1.0036x over previous
//
#include <hip/hip_runtime.h>
#include <stdint.h>

// RobertaSelfAttention: B=4, S=2048, HID=1024, NH=16, HD=64. fp32 in/out.
// R7: attn_k single-barrier software pipeline — KT=64 double-buffer where
// stage(next) is issued BEFORE compute(cur), so the barrier's vmcnt(0) drain
// overlaps ~1800cyc of compute. Mask in LDS (lgkm domain) so mask loads
// don't force the vmcnt queue to drain. Compute body identical to R4.

typedef float f32x4 __attribute__((ext_vector_type(4)));
typedef float f32x16 __attribute__((ext_vector_type(16)));
typedef __bf16 bf16x8 __attribute__((ext_vector_type(8)));
typedef unsigned short ushort_t;
typedef uint32_t u32;

#define MFMA16(a, b, c) __builtin_amdgcn_mfma_f32_16x16x32_bf16(a, b, c, 0, 0, 0)
#define MFMA32(a, b, c) __builtin_amdgcn_mfma_f32_32x32x16_bf16(a, b, c, 0, 0, 0)

__device__ __forceinline__ ushort_t f2b(float f) {
    union { float f; uint32_t u; } x{f};
    uint32_t r = (x.u + 0x7fffu + ((x.u >> 16) & 1u)) >> 16;  // RNE
    return (ushort_t)r;
}

__device__ __forceinline__ float fexp2(float x) {
#if __has_builtin(__builtin_amdgcn_exp2f)
    return __builtin_amdgcn_exp2f(x);
#else
    return exp2f(x);
#endif
}

// pack {bf16(e) lo16, bf16(o) hi16} by byte-perm truncation (e,o > 0)
__device__ __forceinline__ u32 pkpair(float e, float o) {
    union { float f; u32 u; } xe{e}, xo{o};
    return __builtin_amdgcn_perm(xo.u, xe.u, 0x07060302u);
}

__device__ __forceinline__ bf16x8 mk8(u32 a, u32 b, u32 c, u32 d) {
    union { u32 u[4]; bf16x8 v; } x;
    x.u[0] = a; x.u[1] = b; x.u[2] = c; x.u[3] = d;
    return x.v;
}

__device__ __forceinline__ void gld_lds16(const void* g, void* l) {
    __builtin_amdgcn_global_load_lds(
        (const __attribute__((address_space(1))) unsigned int*)g,
        (__attribute__((address_space(3))) unsigned int*)l, 16, 0, 0);
}

// ---------------- fp32 -> bf16 convert: hidden (8M) + Wq/Wk/Wv (3x1M) -------
__global__ __launch_bounds__(256) void convert_k(
    const float* __restrict__ hs, const float* __restrict__ wq,
    const float* __restrict__ wk, const float* __restrict__ wv,
    ushort_t* __restrict__ hs_b, ushort_t* __restrict__ w_b) {
    size_t c = (size_t)blockIdx.x * 256 + threadIdx.x;
    size_t i = c * 8;
    const size_t NHS = (size_t)8192 * 1024;
    const float* src;
    ushort_t* dst;
    if (i < NHS) { src = hs + i; dst = hs_b + i; }
    else {
        size_t j = i - NHS;
        int w = (int)(j >> 20);
        size_t o = j & ((1u << 20) - 1);
        src = (w == 0 ? wq : (w == 1 ? wk : wv)) + o;
        dst = w_b + ((size_t)w << 20) + o;
    }
    float4 a = *(const float4*)src;
    float4 b = *(const float4*)(src + 4);
    uint32_t p0 = (uint32_t)f2b(a.x) | ((uint32_t)f2b(a.y) << 16);
    uint32_t p1 = (uint32_t)f2b(a.z) | ((uint32_t)f2b(a.w) << 16);
    uint32_t p2 = (uint32_t)f2b(b.x) | ((uint32_t)f2b(b.y) << 16);
    uint32_t p3 = (uint32_t)f2b(b.z) | ((uint32_t)f2b(b.w) << 16);
    uint4 v{p0, p1, p2, p3};
    *(uint4*)dst = v;
}

// ---------------- QKV projection GEMM (unchanged from R6) ----------------
__global__ __launch_bounds__(256, 4) void qkv_gemm(
    const ushort_t* __restrict__ Ab, const ushort_t* __restrict__ Wb,
    const float* __restrict__ bq, const float* __restrict__ bk,
    const float* __restrict__ bv, ushort_t* __restrict__ q_ws,
    ushort_t* __restrict__ k_ws, ushort_t* __restrict__ vt_ws) {
    __shared__ __align__(16) char smem_raw[128 * 136 * 2];  // 34816 B
    ushort_t* At = (ushort_t*)smem_raw;        // [128][64]
    ushort_t* Bt = At + 128 * 64;              // [128][64]
    ushort_t* Ct = (ushort_t*)smem_raw;        // [128][stride 136] overlay
    int which = blockIdx.z;
    const ushort_t* W = Wb + ((size_t)which << 20);
    int m0 = blockIdx.y * 128, n0 = blockIdx.x * 128;
    int t = threadIdx.x, lane = t & 63, wave = t >> 6;
    int quad = lane >> 4, l16 = lane & 15;
    int wr = (wave >> 1) * 64, wc = (wave & 1) * 64;
    f32x4 acc[4][4] = {};
    for (int k0 = 0; k0 < 1024; k0 += 64) {
        for (int r = 0; r < 4; r++) {
            int idx = r * 256 + t;
            int row = idx >> 3, co = (idx & 7) * 8;
            gld_lds16(Ab + (size_t)(m0 + row) * 1024 + k0 + co, At + idx * 8);
            gld_lds16(W + (size_t)(n0 + row) * 1024 + k0 + co, Bt + idx * 8);
        }
        asm volatile("s_waitcnt vmcnt(0)" ::: "memory");
        __syncthreads();
        for (int kk = 0; kk < 2; kk++) {
            bf16x8 af[4], bf[4];
            for (int i = 0; i < 4; i++)
                af[i] = *(const bf16x8*)(At + (wr + i * 16 + l16) * 64 + kk * 32 + quad * 8);
            for (int j = 0; j < 4; j++)
                bf[j] = *(const bf16x8*)(Bt + (wc + j * 16 + l16) * 64 + kk * 32 + quad * 8);
            for (int i = 0; i < 4; i++)
                for (int j = 0; j < 4; j++)
                    acc[i][j] = MFMA16(af[i], bf[j], acc[i][j]);
        }
        __syncthreads();
    }
    const float* bias = which == 0 ? bq : (which == 1 ? bk : bv);
    float sc = which == 0 ? (0.125f * 1.44269504f) : 1.0f;  // 1/sqrt(HD)*log2e
    if (which == 2) {
        for (int j = 0; j < 4; j++) {
            float bias_v = bias[n0 + wc + j * 16 + l16];
            for (int i = 0; i < 4; i++) {
                ushort4 pk;
                pk.x = f2b(acc[i][j].x + bias_v);
                pk.y = f2b(acc[i][j].y + bias_v);
                pk.z = f2b(acc[i][j].z + bias_v);
                pk.w = f2b(acc[i][j].w + bias_v);
                *(ushort4*)(Ct + (wc + j * 16 + l16) * 136 + wr + i * 16 + quad * 4) = pk;
            }
        }
    } else {
        for (int j = 0; j < 4; j++) {
            float bias_v = bias[n0 + wc + j * 16 + l16];
            int col = wc + j * 16 + l16;
            for (int i = 0; i < 4; i++) {
                int rb = wr + i * 16 + quad * 4;
                Ct[(rb + 0) * 136 + col] = f2b((acc[i][j].x + bias_v) * sc);
                Ct[(rb + 1) * 136 + col] = f2b((acc[i][j].y + bias_v) * sc);
                Ct[(rb + 2) * 136 + col] = f2b((acc[i][j].z + bias_v) * sc);
                Ct[(rb + 3) * 136 + col] = f2b((acc[i][j].w + bias_v) * sc);
            }
        }
    }
    __syncthreads();
    for (int r = 0; r < 8; r++) {
        int idx = r * 256 + t;
        int row = idx >> 4, c8 = (idx & 15) * 8;
        uint4 val = *(const uint4*)(Ct + row * 136 + c8);
        if (which == 2) {
            int col = n0 + row, h = col >> 6, d = col & 63;
            int tok = m0 + c8, b = tok >> 11, s = tok & 2047;
            *(uint4*)(vt_ws + ((size_t)(b * 16 + h) * 64 + d) * 2048 + s) = val;
        } else {
            int tok = m0 + row, b = tok >> 11, s = tok & 2047;
            int col = n0 + c8, h = col >> 6, d = col & 63;
            ushort_t* base = which == 0 ? q_ws : k_ws;
            *(uint4*)(base + ((size_t)(b * 16 + h) * 2048 + s) * 64 + d) = val;
        }
    }
}

// ---------------- flash attention: R4 body + single-barrier pipeline -------
__global__ __launch_bounds__(256, 2) void attn_k(
    const ushort_t* __restrict__ q_ws, const ushort_t* __restrict__ k_ws,
    const ushort_t* __restrict__ vt_ws, const float* __restrict__ mask,
    float* __restrict__ out) {
    // buf i at smraw+i*16384: Kl [64key][64d] 8KB + Vtl [64d][64key] 8KB,
    // both mod-8 xor-chunk swizzled. Mask f32[2048]*log2e at +32768.
    // Epilogue overlay Ow [128][65] f32 over buffers.
    __shared__ __align__(16) char smraw[40960];
    float* Ml = (float*)(smraw + 32768);
    float* Ow = (float*)smraw;

    int bh = blockIdx.y, b = bh >> 4, h = bh & 15;
    int q0 = blockIdx.x * 256;
    int t = threadIdx.x, lane = t & 63, w = t >> 6;
    int l31 = lane & 31, hi = lane >> 5;
    bool h0 = (hi == 0);
    const ushort_t* Q = q_ws + (size_t)bh * 2048 * 64;
    const ushort_t* K = k_ws + (size_t)bh * 2048 * 64;
    const ushort_t* Vt = vt_ws + (size_t)bh * 64 * 2048;

    // mask * log2e into LDS (lgkm domain — keeps vmcnt queue clean in-loop)
    for (int r = 0; r < 8; r++) {
        int i = r * 256 + t;
        Ml[i] = mask[b * 2048 + i] * 1.44269504f;
    }

    bf16x8 qf[2][4];
#pragma unroll
    for (int qg = 0; qg < 2; qg++)
#pragma unroll
        for (int cs = 0; cs < 4; cs++)
            qf[qg][cs] = *(const bf16x8*)(
                Q + (size_t)(q0 + w * 64 + qg * 32 + l31) * 64 + cs * 16 + hi * 8);
    int co[4];
#pragma unroll
    for (int cs = 0; cs < 4; cs++) co[cs] = ((cs * 2 + hi) ^ (l31 & 7)) * 8;

    f32x16 o00 = {}, o01 = {}, o10 = {}, o11 = {};
    float rs0 = 0.f, rs1 = 0.f;

    auto stage = [&](int bufi, int t0) {
        ushort_t* Klb = (ushort_t*)(smraw + bufi * 16384);
        ushort_t* Vtlb = Klb + 4096;
#pragma unroll
        for (int it = 0; it < 2; it++) {
            int idx = it * 256 + t;
            int row = idx >> 3, ch = idx & 7;
            int sch = (ch ^ (row & 7)) * 8;
            gld_lds16(K + (size_t)(t0 + row) * 64 + sch, Klb + idx * 8);
            gld_lds16(Vt + (size_t)row * 2048 + t0 + sch, Vtlb + idx * 8);
        }
    };

    stage(0, 0);
    asm volatile("s_waitcnt vmcnt(0)" ::: "memory");
    __syncthreads();
    int buf = 0;
    for (int t0 = 0; t0 < 2048; t0 += 64) {
        // prefetch next tile FIRST — its drain overlaps this tile's compute
        if (t0 + 64 < 2048) stage(buf ^ 1, t0 + 64);
        const ushort_t* Kl = (const ushort_t*)(smraw + buf * 16384);
        const ushort_t* Vtl = Kl + 4096;
        // S^T = K · Q^T for both q-groups (K frags shared)
        f32x16 s00 = {}, s01 = {}, s10 = {}, s11 = {};
#pragma unroll
        for (int cs = 0; cs < 4; cs++) {
            bf16x8 k0 = *(const bf16x8*)(Kl + l31 * 64 + co[cs]);
            bf16x8 k1 = *(const bf16x8*)(Kl + (32 + l31) * 64 + co[cs]);
            s00 = MFMA32(k0, qf[0][cs], s00);
            s01 = MFMA32(k1, qf[0][cs], s01);
            s10 = MFMA32(k0, qf[1][cs], s10);
            s11 = MFMA32(k1, qf[1][cs], s11);
        }
        // exp2 + pack + P^T B-frags per q-group (mask from LDS, broadcast)
        bf16x8 pfr[2][4];
#pragma unroll
        for (int qg = 0; qg < 2; qg++) {
            const f32x16& sa = qg ? s10 : s00;
            const f32x16& sb = qg ? s11 : s01;
            u32 pa[8], pb[8];
            float rst = 0.f;
#pragma unroll
            for (int i = 0; i < 4; i++) {
                f32x4 bm = *(const f32x4*)(Ml + t0 + 8 * i + 4 * hi);
                float e0 = fexp2(sa[4 * i + 0] + bm[0]);
                float e1 = fexp2(sa[4 * i + 1] + bm[1]);
                float e2 = fexp2(sa[4 * i + 2] + bm[2]);
                float e3 = fexp2(sa[4 * i + 3] + bm[3]);
                rst += (e0 + e1) + (e2 + e3);
                pa[2 * i] = pkpair(e0, e1);
                pa[2 * i + 1] = pkpair(e2, e3);
            }
#pragma unroll
            for (int i = 0; i < 4; i++) {
                f32x4 bm = *(const f32x4*)(Ml + t0 + 32 + 8 * i + 4 * hi);
                float e0 = fexp2(sb[4 * i + 0] + bm[0]);
                float e1 = fexp2(sb[4 * i + 1] + bm[1]);
                float e2 = fexp2(sb[4 * i + 2] + bm[2]);
                float e3 = fexp2(sb[4 * i + 3] + bm[3]);
                rst += (e0 + e1) + (e2 + e3);
                pb[2 * i] = pkpair(e0, e1);
                pb[2 * i + 1] = pkpair(e2, e3);
            }
            if (qg == 0) rs0 += rst; else rs1 += rst;
#pragma unroll
            for (int g = 0; g < 4; g++) {
                const u32* aa = (g < 2) ? pa : pb;
                int base = (g & 1) * 4;
                u32 y0 = h0 ? aa[base + 2] : aa[base + 0];
                u32 y1 = h0 ? aa[base + 3] : aa[base + 1];
                u32 sy0 = (u32)__shfl_xor((int)y0, 32, 64);
                u32 sy1 = (u32)__shfl_xor((int)y1, 32, 64);
                pfr[qg][g] = mk8(h0 ? aa[base + 0] : sy0, h0 ? aa[base + 1] : sy1,
                                 h0 ? sy0 : aa[base + 2], h0 ? sy1 : aa[base + 3]);
            }
        }
        // O^T += V^T · P^T for both q-groups (V frags shared)
#pragma unroll
        for (int cs = 0; cs < 4; cs++) {
            bf16x8 v0 = *(const bf16x8*)(Vtl + l31 * 64 + co[cs]);
            bf16x8 v1 = *(const bf16x8*)(Vtl + (32 + l31) * 64 + co[cs]);
            o00 = MFMA32(v0, pfr[0][cs], o00);
            o01 = MFMA32(v1, pfr[0][cs], o01);
            o10 = MFMA32(v0, pfr[1][cs], o10);
            o11 = MFMA32(v1, pfr[1][cs], o11);
        }
        // single barrier: drains the (already-complete) prefetch + publishes
        __syncthreads();
        buf ^= 1;
    }
    rs0 += __shfl_xor(rs0, 32, 64);
    rs1 += __shfl_xor(rs1, 32, 64);
    float inv0 = 1.f / rs0, inv1 = 1.f / rs1;
    // epilogue: per q-group, O^T -> LDS transpose -> coalesced f32x4 stores
#pragma unroll
    for (int qg = 0; qg < 2; qg++) {
        float inv = qg ? inv1 : inv0;
        const f32x16& a0 = qg ? o10 : o00;
        const f32x16& a1 = qg ? o11 : o01;
#pragma unroll
        for (int g = 0; g < 4; g++) {
            f32x4 c0, c1;
#pragma unroll
            for (int r = 0; r < 4; r++) {
                c0[r] = a0[4 * g + r] * inv;
                c1[r] = a1[4 * g + r] * inv;
            }
            *(f32x4*)(Ow + (w * 32 + l31) * 65 + 8 * g + 4 * hi) = c0;
            *(f32x4*)(Ow + (w * 32 + l31) * 65 + 32 + 8 * g + 4 * hi) = c1;
        }
        __syncthreads();
#pragma unroll
        for (int cc = 0; cc < 8; cc++) {
            int c = cc * 256 + t;
            int row = c >> 4, seg = (c & 15) * 4;
            f32x4 vv = *(const f32x4*)(Ow + row * 65 + seg);
            int ql = (row >> 5) * 64 + qg * 32 + (row & 31);
            *(f32x4*)(out + ((size_t)(b * 2048 + q0 + ql)) * 1024 + h * 64 + seg) = vv;
        }
        __syncthreads();
    }
}

extern "C" void kernel_launch(void* const* d_in, const int* in_sizes, int n_in,
                              void* d_out, int out_size, void* d_ws, size_t ws_size,
                              hipStream_t stream) {
    const float* hs = (const float*)d_in[0];
    const float* mask = (const float*)d_in[1];
    const float* wq = (const float*)d_in[2];
    const float* bq = (const float*)d_in[3];
    const float* wk = (const float*)d_in[4];
    const float* bk = (const float*)d_in[5];
    const float* wv = (const float*)d_in[6];
    const float* bv = (const float*)d_in[7];
    float* out = (float*)d_out;
    char* ws = (char*)d_ws;
    ushort_t* hs_b = (ushort_t*)ws;
    ushort_t* w_b = (ushort_t*)(ws + 16777216);
    ushort_t* q_ws = (ushort_t*)(ws + 23068672);
    ushort_t* k_ws = (ushort_t*)(ws + 39845888);
    ushort_t* vt_ws = (ushort_t*)(ws + 56623104);

    convert_k<<<5632, 256, 0, stream>>>(hs, wq, wk, wv, hs_b, w_b);
    qkv_gemm<<<dim3(8, 64, 3), 256, 0, stream>>>(hs_b, w_b, bq, bk, bv, q_ws, k_ws, vt_ws);
    attn_k<<<dim3(8, 64), 256, 0, stream>>>(q_ws, k_ws, vt_ws, mask, out);
}